// Round 1
// baseline (378.818 us; speedup 1.0000x reference)
//
#include <hip/hip_runtime.h>
#include <math.h>

// Problem dims (fixed by reference setup_inputs)
constexpr int B_ = 8;
constexpr int C_ = 256;
constexpr int N_ = 2048;
constexpr int CN_ = C_ * N_;        // 524288
constexpr int TOT_ = B_ * C_ * N_;  // 4194304 (size of one output tensor)
constexpr int NSPLIT = 4;           // m-range split for gram blocks
constexpr int MRANGE = N_ / NSPLIT; // 512

// ws layout (in floats):
//   [0,      16384)   rnorm[b][n]
//   [16384,  81920)   partial best val [b][s][n]
//   [81920, 147456)   partial best idx [b][s][n] (int)
//   [147456,163840)   final idx [b][n] (int)

// ---------------------------------------------------------------- norms ----
__global__ __launch_bounds__(256) void norms_kernel(const float* __restrict__ x,
                                                    float* __restrict__ rnorm) {
    const int blk = blockIdx.x;            // B_ * (N_/64) = 256
    const int batch = blk >> 5;
    const int n0 = (blk & 31) << 6;
    const int i = threadIdx.x & 63;
    const int j = threadIdx.x >> 6;
    const float* xp = x + batch * CN_ + n0 + i;
    float s = 0.f;
    for (int c = j * 64; c < j * 64 + 64; ++c) {
        float v = xp[c * N_];
        s += v * v;
    }
    __shared__ float red[4][64];
    red[j][i] = s;
    __syncthreads();
    if (j == 0) {
        float t = red[0][i] + red[1][i] + red[2][i] + red[3][i];
        // reference: sum(x*x + 1e-6) = sum(x*x) + C*1e-6
        rnorm[batch * N_ + n0 + i] = 1.0f / sqrtf(t + 256.0f * 1e-6f);
    }
}

// ---------------------------------------------------- gram + argmax --------
// grid = B_ * (N_/64) * NSPLIT = 1024 blocks, 256 threads.
// blockIdx.x = ((batch*32 + ntile)*NSPLIT + s)
// Each block: 64 n-rows vs m-range of 512, K = 256, fp32 tiled matmul with
// fused running-argmax of sim[n][m] * rnorm[m] (diagonal excluded).
__global__ __launch_bounds__(256) void gram_argmax_kernel(
        const float* __restrict__ x, const float* __restrict__ rnorm,
        float* __restrict__ pval, int* __restrict__ pidx) {
    const int blk = blockIdx.x;
    const int s = blk & 3;
    const int nt = (blk >> 2) & 31;
    const int batch = blk >> 7;
    const int n0 = nt << 6;
    const int m_base = s * MRANGE;
    const float* xb = x + batch * CN_;

    __shared__ float As[16][64];
    __shared__ float Bs[16][64];
    __shared__ float rv[16][64];
    __shared__ int ri[16][64];

    const int tid = threadIdx.x;
    const int a = tid & 15;    // n micro-group (4 rows: a*4..a*4+3)
    const int bg = tid >> 4;   // m micro-group (4 cols: bg*4..bg*4+3)
    const int lcol = tid & 63; // staging column
    const int lrow = tid >> 6; // staging row base

    float bestv[4];
    int besti[4];
#pragma unroll
    for (int p = 0; p < 4; ++p) {
        bestv[p] = -3.4e38f;
        besti[p] = 0;
    }

    for (int mt = 0; mt < MRANGE / 64; ++mt) {
        const int m0 = m_base + mt * 64;
        float acc[4][4];
#pragma unroll
        for (int p = 0; p < 4; ++p)
#pragma unroll
            for (int q = 0; q < 4; ++q) acc[p][q] = 0.f;

        for (int c0 = 0; c0 < C_; c0 += 16) {
            __syncthreads();
#pragma unroll
            for (int r = 0; r < 4; ++r) {
                const int cr = lrow + r * 4;
                As[cr][lcol] = xb[(c0 + cr) * N_ + n0 + lcol];
                Bs[cr][lcol] = xb[(c0 + cr) * N_ + m0 + lcol];
            }
            __syncthreads();
#pragma unroll
            for (int k = 0; k < 16; ++k) {
                float av[4], bv[4];
#pragma unroll
                for (int p = 0; p < 4; ++p) av[p] = As[k][a * 4 + p];
#pragma unroll
                for (int q = 0; q < 4; ++q) bv[q] = Bs[k][bg * 4 + q];
#pragma unroll
                for (int p = 0; p < 4; ++p)
#pragma unroll
                    for (int q = 0; q < 4; ++q) acc[p][q] += av[p] * bv[q];
            }
        }
        // fused argmax update (scan m ascending; strict > keeps first max)
#pragma unroll
        for (int q = 0; q < 4; ++q) {
            const int m = m0 + bg * 4 + q;
            const float rn = rnorm[batch * N_ + m];
#pragma unroll
            for (int p = 0; p < 4; ++p) {
                const int n = n0 + a * 4 + p;
                const float v = acc[p][q] * rn;
                if (m != n && v > bestv[p]) {
                    bestv[p] = v;
                    besti[p] = m;
                }
            }
        }
    }

    __syncthreads();
#pragma unroll
    for (int p = 0; p < 4; ++p) {
        rv[bg][a * 4 + p] = bestv[p];
        ri[bg][a * 4 + p] = besti[p];
    }
    __syncthreads();
    if (tid < 64) {
        float bv2 = rv[0][tid];
        int bi2 = ri[0][tid];
        for (int g = 1; g < 16; ++g) {
            const float v = rv[g][tid];
            const int ii = ri[g][tid];
            // cross-thread m-sets interleave: tie-break to lowest index
            if (v > bv2 || (v == bv2 && ii < bi2)) {
                bv2 = v;
                bi2 = ii;
            }
        }
        pval[(batch * NSPLIT + s) * N_ + n0 + tid] = bv2;
        pidx[(batch * NSPLIT + s) * N_ + n0 + tid] = bi2;
    }
}

// -------------------------------------------------------------- combine ----
__global__ void combine_kernel(const float* __restrict__ pval,
                               const int* __restrict__ pidx,
                               int* __restrict__ fidx) {
    const int t = blockIdx.x * 256 + threadIdx.x;  // 0..B_*N_
    const int batch = t >> 11;
    const int n = t & 2047;
    float bv = -3.4e38f;
    int bi = 0;
    for (int s = 0; s < NSPLIT; ++s) {
        const float v = pval[(batch * NSPLIT + s) * N_ + n];
        const int ii = pidx[(batch * NSPLIT + s) * N_ + n];
        if (v > bv || (v == bv && ii < bi)) {
            bv = v;
            bi = ii;
        }
    }
    fidx[t] = bi;
}

// ------------------------------------------- gather + gate + outputs -------
// grid = B_ * (N_/64) = 256 blocks, 256 threads. thread = (i = n lane, j = stripe)
__global__ __launch_bounds__(256) void fuse_kernel(const float* __restrict__ x,
                                                   const float* __restrict__ W,
                                                   const int* __restrict__ fidx,
                                                   float* __restrict__ out) {
    const int blk = blockIdx.x;
    const int batch = blk >> 5;
    const int n0 = (blk & 31) << 6;
    const int i = threadIdx.x & 63;
    const int j = threadIdx.x >> 6;

    __shared__ float Wl[1024];  // W[2][512] row-major
    __shared__ int il[64];
    __shared__ float l0r[4][64], l1r[4][64];
    __shared__ float w0s[64], w1s[64];

    for (int t = threadIdx.x; t < 1024; t += 256) Wl[t] = W[t];
    if (threadIdx.x < 64) il[threadIdx.x] = fidx[batch * N_ + n0 + threadIdx.x];
    __syncthreads();

    const float* xb = x + batch * CN_;
    const int myidx = il[i];

    // logits: l_k = sum_c x[c,n]*W[k,c] + f_re[c,n]*W[k,256+c]
    float l0 = 0.f, l1 = 0.f;
    for (int c = j * 64; c < j * 64 + 64; ++c) {
        const float xv = xb[c * N_ + n0 + i];
        const float fv = xb[c * N_ + myidx];
        l0 += xv * Wl[c] + fv * Wl[256 + c];
        l1 += xv * Wl[512 + c] + fv * Wl[768 + c];
    }
    l0r[j][i] = l0;
    l1r[j][i] = l1;
    __syncthreads();
    if (j == 0) {
        const float L0 = l0r[0][i] + l0r[1][i] + l0r[2][i] + l0r[3][i];
        const float L1 = l1r[0][i] + l1r[1][i] + l1r[2][i] + l1r[3][i];
        const float mx = fmaxf(L0, L1);
        const float e0 = expf(L0 - mx);
        const float e1 = expf(L1 - mx);
        const float inv = 1.0f / (e0 + e1);
        w0s[i] = e0 * inv;
        w1s[i] = e1 * inv;
    }
    __syncthreads();
    const float w0 = w0s[i];
    const float w1 = w1s[i];

    // outputs: out at [0, TOT_), f_re at [TOT_, 2*TOT_)
    for (int c = j; c < C_; c += 4) {
        const int off = batch * CN_ + c * N_ + n0 + i;
        const float xv = xb[c * N_ + n0 + i];
        const float fv = xb[c * N_ + myidx];
        out[off] = xv * w0 + fv * w1;
        out[TOT_ + off] = fv;
    }
}

// ---------------------------------------------------------------------------
extern "C" void kernel_launch(void* const* d_in, const int* in_sizes, int n_in,
                              void* d_out, int out_size, void* d_ws, size_t ws_size,
                              hipStream_t stream) {
    const float* x = (const float*)d_in[0];
    const float* W = (const float*)d_in[1];
    float* out = (float*)d_out;
    float* ws = (float*)d_ws;

    float* rnorm = ws;                    // 16384 floats
    float* pval = ws + 16384;             // 65536 floats
    int* pidx = (int*)(ws + 81920);       // 65536 ints
    int* fidx = (int*)(ws + 147456);      // 16384 ints

    norms_kernel<<<B_ * (N_ / 64), 256, 0, stream>>>(x, rnorm);
    gram_argmax_kernel<<<B_ * (N_ / 64) * NSPLIT, 256, 0, stream>>>(x, rnorm, pval, pidx);
    combine_kernel<<<(B_ * N_) / 256, 256, 0, stream>>>(pval, pidx, fidx);
    fuse_kernel<<<B_ * (N_ / 64), 256, 0, stream>>>(x, W, fidx, out);
}

// Round 2
// 280.866 us; speedup vs baseline: 1.3488x; 1.3488x over previous
//
#include <hip/hip_runtime.h>
#include <hip/hip_bf16.h>
#include <math.h>

constexpr int B_ = 8;
constexpr int C_ = 256;
constexpr int N_ = 2048;
constexpr int CN_ = C_ * N_;        // 524288
constexpr int TOT_ = B_ * C_ * N_;  // 4194304

typedef __attribute__((ext_vector_type(8))) short bf16x8;
typedef __attribute__((ext_vector_type(4))) float f32x4;

__device__ __forceinline__ void g2l16(const void* g, void* l) {
    __builtin_amdgcn_global_load_lds(
        (const __attribute__((address_space(1))) void*)g,
        (__attribute__((address_space(3))) void*)l, 16, 0, 0);
}

// ------------------------------------------------------------- convert -----
// x[b][c][n] fp32 -> xT[b][n][c] fp32 (optional), hiT/loT[b][n][c] bf16 split
template <bool USE_XT>
__global__ __launch_bounds__(256) void convert_kernel(const float* __restrict__ x,
                                                      float* __restrict__ xT,
                                                      __hip_bfloat16* __restrict__ hiT,
                                                      __hip_bfloat16* __restrict__ loT) {
    const int blk = blockIdx.x;  // batch*128 + ctile*32 + ntile
    const int nt = blk & 31, ctile = (blk >> 5) & 3, batch = blk >> 7;
    const int n0 = nt << 6, c0 = ctile << 6;
    __shared__ float tb[64][65];
    const int t = threadIdx.x;
    const int ni = t & 63, cb = t >> 6;
#pragma unroll 4
    for (int r = 0; r < 16; ++r) {
        const int ci = cb + r * 4;
        tb[ci][ni] = x[(size_t)batch * CN_ + (size_t)(c0 + ci) * N_ + n0 + ni];
    }
    __syncthreads();
    const int ci2 = t & 63, nb = t >> 6;
#pragma unroll 4
    for (int r = 0; r < 16; ++r) {
        const int ni2 = nb + r * 4;
        const float v = tb[ci2][ni2];
        const size_t o = ((size_t)batch * N_ + n0 + ni2) * C_ + c0 + ci2;
        const __hip_bfloat16 h = __float2bfloat16(v);
        const float hf = __bfloat162float(h);
        hiT[o] = h;
        loT[o] = __float2bfloat16(v - hf);
        if constexpr (USE_XT) xT[o] = v;
    }
}

// --------------------------------------------------------------- norms -----
__global__ __launch_bounds__(256) void norms_kernel(const float* __restrict__ x,
                                                    float* __restrict__ rnorm) {
    const int blk = blockIdx.x;  // 256
    const int batch = blk >> 5;
    const int n0 = (blk & 31) << 6;
    const int i = threadIdx.x & 63;
    const int j = threadIdx.x >> 6;
    const float* xp = x + (size_t)batch * CN_ + n0 + i;
    float s = 0.f;
    for (int c = j * 64; c < j * 64 + 64; ++c) {
        const float v = xp[(size_t)c * N_];
        s += v * v;
    }
    __shared__ float red[4][64];
    red[j][i] = s;
    __syncthreads();
    if (j == 0) {
        const float t = red[0][i] + red[1][i] + red[2][i] + red[3][i];
        rnorm[batch * N_ + n0 + i] = 1.0f / sqrtf(t + 256.0f * 1e-6f);
    }
}

// ---------------------------------------------- gram (MFMA) + argmax -------
// grid = B * 16 * 16 = 2048 blocks of 256 (4 waves). 128x128 output tile.
// sim = hiT*hiT + hiT*loT + loT*hiT  (3 segments of K=256 each)
__global__ __launch_bounds__(256) void gram_mfma_kernel(
        const __hip_bfloat16* __restrict__ hiT, const __hip_bfloat16* __restrict__ loT,
        const float* __restrict__ rnorm,
        float* __restrict__ pval, int* __restrict__ pidx, float* __restrict__ pval2) {
    const int blk = blockIdx.x;
    const int bm = blk & 15;
    const int bn = (blk >> 4) & 15;
    const int batch = blk >> 8;
    const int n0 = bn << 7, m0 = bm << 7;

    __shared__ short As[128 * 32];  // [n-row][k] bf16, 64B rows
    __shared__ short Bs[128 * 32];  // [m-row][k]
    __shared__ float rv1[128][2];
    __shared__ int ri1[128][2];
    __shared__ float rv2[128][2];

    const int tid = threadIdx.x;
    const int l = tid & 63, w = tid >> 6;
    const int lm = l & 15, q = l >> 4;
    const int wn = (w >> 1) << 6, wm = (w & 1) << 6;

    f32x4 acc[4][4];
#pragma unroll
    for (int rt = 0; rt < 4; ++rt)
#pragma unroll
        for (int ct = 0; ct < 4; ++ct) acc[rt][ct] = (f32x4){0.f, 0.f, 0.f, 0.f};

    const size_t bbase = (size_t)batch * CN_;
    const int srow = tid >> 2;         // 0..63 (staging row)
    const int slane = (tid & 3) << 3;  // k-element offset {0,8,16,24}

    for (int seg = 0; seg < 3; ++seg) {
        const __hip_bfloat16* Asrc = (seg == 2) ? loT : hiT;
        const __hip_bfloat16* Bsrc = (seg == 1) ? loT : hiT;
        for (int kt = 0; kt < 8; ++kt) {
            const int kk = kt << 5;
            __syncthreads();
            const __hip_bfloat16* ga0 = Asrc + bbase + (size_t)(n0 + srow) * C_ + kk + slane;
            const __hip_bfloat16* gb0 = Bsrc + bbase + (size_t)(m0 + srow) * C_ + kk + slane;
            g2l16(ga0, As + tid * 8);
            g2l16(ga0 + 64 * C_, As + 2048 + tid * 8);
            g2l16(gb0, Bs + tid * 8);
            g2l16(gb0 + 64 * C_, Bs + 2048 + tid * 8);
            __syncthreads();

            bf16x8 af[4], bfr[4];
#pragma unroll
            for (int rt = 0; rt < 4; ++rt)
                af[rt] = *(const bf16x8*)(As + (wn + rt * 16 + lm) * 32 + q * 8);
#pragma unroll
            for (int ct = 0; ct < 4; ++ct)
                bfr[ct] = *(const bf16x8*)(Bs + (wm + ct * 16 + lm) * 32 + q * 8);
#pragma unroll
            for (int rt = 0; rt < 4; ++rt)
#pragma unroll
                for (int ct = 0; ct < 4; ++ct)
                    acc[rt][ct] = __builtin_amdgcn_mfma_f32_16x16x32_bf16(
                        af[rt], bfr[ct], acc[rt][ct], 0, 0, 0);
        }
    }

    // epilogue: scaled running argmax (best + second-best), diag excluded.
    float rn[4];
#pragma unroll
    for (int ct = 0; ct < 4; ++ct) rn[ct] = rnorm[batch * N_ + m0 + wm + ct * 16 + lm];

#pragma unroll
    for (int rt = 0; rt < 4; ++rt) {
#pragma unroll
        for (int r = 0; r < 4; ++r) {
            const int nrow = n0 + wn + rt * 16 + q * 4 + r;
            float v1 = -3.4e38f, v2 = -3.4e38f;
            int i1 = 0x7fffffff;
#pragma unroll
            for (int ct = 0; ct < 4; ++ct) {
                const int m = m0 + wm + ct * 16 + lm;
                const float v = acc[rt][ct][r] * rn[ct];
                if (m == nrow) continue;
                if (v > v1) { v2 = v1; v1 = v; i1 = m; }
                else if (v > v2) v2 = v;
            }
#pragma unroll
            for (int d = 1; d < 16; d <<= 1) {
                const float ov1 = __shfl_xor(v1, d, 64);
                const int oi1 = __shfl_xor(i1, d, 64);
                const float ov2 = __shfl_xor(v2, d, 64);
                if (ov1 > v1 || (ov1 == v1 && oi1 < i1)) {
                    v2 = fmaxf(v1, ov2); v1 = ov1; i1 = oi1;
                } else {
                    v2 = fmaxf(v2, ov1);
                }
            }
            if (lm == 0) {
                const int rloc = wn + rt * 16 + q * 4 + r;
                rv1[rloc][w & 1] = v1;
                ri1[rloc][w & 1] = i1;
                rv2[rloc][w & 1] = v2;
            }
        }
    }
    __syncthreads();
    if (tid < 128) {
        float v1 = rv1[tid][0]; int i1 = ri1[tid][0]; float v2 = rv2[tid][0];
        const float ov1 = rv1[tid][1]; const int oi1 = ri1[tid][1]; const float ov2 = rv2[tid][1];
        if (ov1 > v1 || (ov1 == v1 && oi1 < i1)) { v2 = fmaxf(v1, ov2); v1 = ov1; i1 = oi1; }
        else v2 = fmaxf(v2, ov1);
        const size_t gi = (size_t)(batch * 16 + bm) * N_ + n0 + tid;
        pval[gi] = v1; pidx[gi] = i1; pval2[gi] = v2;
    }
}

// -------------------------------------------------------------- combine ----
__global__ void combine_kernel(const float* __restrict__ pval, const int* __restrict__ pidx,
                               const float* __restrict__ pval2, int* __restrict__ fidx,
                               int* __restrict__ rcnt, int* __restrict__ ridx) {
    const int t = blockIdx.x * 256 + threadIdx.x;  // 16384
    const int batch = t >> 11, n = t & 2047;
    float v1 = -3.4e38f, v2 = -3.4e38f;
    int i1 = 0x7fffffff;
    for (int s = 0; s < 16; ++s) {
        const size_t gi = (size_t)(batch * 16 + s) * N_ + n;
        const float ov1 = pval[gi]; const int oi1 = pidx[gi]; const float ov2 = pval2[gi];
        if (ov1 > v1 || (ov1 == v1 && oi1 < i1)) { v2 = fmaxf(v1, ov2); v1 = ov1; i1 = oi1; }
        else v2 = fmaxf(v2, ov1);
    }
    fidx[t] = i1;
    if (v1 - v2 < 1e-4f) {
        const int slot = atomicAdd(rcnt, 1);
        ridx[slot] = t;
    }
}

// --------------------------------------------------------------- rescue ----
template <bool USE_XT>
__device__ __forceinline__ float loadT(const float* xT, const __hip_bfloat16* hiT,
                                       const __hip_bfloat16* loT, size_t idx) {
    if constexpr (USE_XT) return xT[idx];
    else return __bfloat162float(hiT[idx]) + __bfloat162float(loT[idx]);
}

template <bool USE_XT>
__global__ __launch_bounds__(256) void rescue_kernel(const float* __restrict__ xT,
                                                     const __hip_bfloat16* __restrict__ hiT,
                                                     const __hip_bfloat16* __restrict__ loT,
                                                     const float* __restrict__ rnorm,
                                                     const int* __restrict__ rcnt,
                                                     const int* __restrict__ ridx,
                                                     int* __restrict__ fidx) {
    const int cnt = *rcnt;
    const int tid = threadIdx.x;
    __shared__ float xrow[256];
    __shared__ float bv[256];
    __shared__ int bi[256];
    for (int rr = blockIdx.x; rr < cnt; rr += gridDim.x) {
        const int t = ridx[rr];
        const int batch = t >> 11, n = t & 2047;
        xrow[tid] = loadT<USE_XT>(xT, hiT, loT, ((size_t)batch * N_ + n) * C_ + tid);
        __syncthreads();
        float best = -3.4e38f;
        int besti = 0x7fffffff;
        for (int mm = tid; mm < N_; mm += 256) {
            const size_t mb = ((size_t)batch * N_ + mm) * C_;
            float s = 0.f;
            for (int c = 0; c < C_; ++c) s += xrow[c] * loadT<USE_XT>(xT, hiT, loT, mb + c);
            const float v = s * rnorm[batch * N_ + mm];
            if (mm != n && v > best) { best = v; besti = mm; }
        }
        bv[tid] = best; bi[tid] = besti;
        __syncthreads();
        for (int sft = 128; sft > 0; sft >>= 1) {
            if (tid < sft) {
                const float ov = bv[tid + sft]; const int oi = bi[tid + sft];
                if (ov > bv[tid] || (ov == bv[tid] && oi < bi[tid])) { bv[tid] = ov; bi[tid] = oi; }
            }
            __syncthreads();
        }
        if (tid == 0) fidx[t] = bi[0];
        __syncthreads();
    }
}

// ------------------------------------------- gather + gate + outputs -------
template <bool USE_XT>
__global__ __launch_bounds__(256) void fuse_kernel(const float* __restrict__ x,
                                                   const float* __restrict__ xT,
                                                   const __hip_bfloat16* __restrict__ hiT,
                                                   const __hip_bfloat16* __restrict__ loT,
                                                   const float* __restrict__ W,
                                                   const int* __restrict__ fidx,
                                                   float* __restrict__ out) {
    const int blk = blockIdx.x;
    const int batch = blk >> 5;
    const int n0 = (blk & 31) << 6;
    const int i = threadIdx.x & 63;
    const int j = threadIdx.x >> 6;

    __shared__ float Wl[1024];
    __shared__ int il[64];
    __shared__ float l0r[4][64], l1r[4][64];
    __shared__ float w0s[64], w1s[64];

    for (int t = threadIdx.x; t < 1024; t += 256) Wl[t] = W[t];
    if (threadIdx.x < 64) il[threadIdx.x] = fidx[batch * N_ + n0 + threadIdx.x];
    __syncthreads();

    const float* xb = x + (size_t)batch * CN_;
    const int myidx = il[i];
    const size_t tb = ((size_t)batch * N_ + myidx) * C_;

    float l0 = 0.f, l1 = 0.f;
    for (int c = j * 64; c < j * 64 + 64; ++c) {
        const float xv = xb[(size_t)c * N_ + n0 + i];
        const float fv = loadT<USE_XT>(xT, hiT, loT, tb + c);
        l0 += xv * Wl[c] + fv * Wl[256 + c];
        l1 += xv * Wl[512 + c] + fv * Wl[768 + c];
    }
    l0r[j][i] = l0;
    l1r[j][i] = l1;
    __syncthreads();
    if (j == 0) {
        const float L0 = l0r[0][i] + l0r[1][i] + l0r[2][i] + l0r[3][i];
        const float L1 = l1r[0][i] + l1r[1][i] + l1r[2][i] + l1r[3][i];
        const float mx = fmaxf(L0, L1);
        const float e0 = expf(L0 - mx);
        const float e1 = expf(L1 - mx);
        const float inv = 1.0f / (e0 + e1);
        w0s[i] = e0 * inv;
        w1s[i] = e1 * inv;
    }
    __syncthreads();
    const float w0 = w0s[i];
    const float w1 = w1s[i];

    for (int c = j * 64; c < j * 64 + 64; ++c) {
        const size_t off = (size_t)batch * CN_ + (size_t)c * N_ + n0 + i;
        const float xv = xb[(size_t)c * N_ + n0 + i];
        const float fv = loadT<USE_XT>(xT, hiT, loT, tb + c);
        out[off] = xv * w0 + fv * w1;
        out[TOT_ + off] = fv;
    }
}

// ---------------------------------------------------------------------------
extern "C" void kernel_launch(void* const* d_in, const int* in_sizes, int n_in,
                              void* d_out, int out_size, void* d_ws, size_t ws_size,
                              hipStream_t stream) {
    const float* x = (const float*)d_in[0];
    const float* W = (const float*)d_in[1];
    float* out = (float*)d_out;

    // ws layout
    const size_t XT_BYTES = (size_t)TOT_ * 4;       // 16.78 MB
    const size_t BF_BYTES = (size_t)TOT_ * 2;       // 8.39 MB each
    const size_t NORM_BYTES = (size_t)B_ * N_ * 4;  // 64 KB
    const size_t P_BYTES = (size_t)B_ * 16 * N_ * 4;  // 1 MB each
    const size_t need_lite = 2 * BF_BYTES + NORM_BYTES + 3 * P_BYTES + 2 * NORM_BYTES + 256;
    const bool use_xt = (ws_size >= need_lite + XT_BYTES);

    uint8_t* p = (uint8_t*)d_ws;
    float* xT = nullptr;
    if (use_xt) { xT = (float*)p; p += XT_BYTES; }
    __hip_bfloat16* hiT = (__hip_bfloat16*)p; p += BF_BYTES;
    __hip_bfloat16* loT = (__hip_bfloat16*)p; p += BF_BYTES;
    float* rnorm = (float*)p; p += NORM_BYTES;
    float* pval = (float*)p; p += P_BYTES;
    int* pidx = (int*)p; p += P_BYTES;
    float* pval2 = (float*)p; p += P_BYTES;
    int* fidx = (int*)p; p += NORM_BYTES;
    int* rcnt = (int*)p; p += 256;
    int* ridx = (int*)p; p += NORM_BYTES;

    if (use_xt)
        convert_kernel<true><<<1024, 256, 0, stream>>>(x, xT, hiT, loT);
    else
        convert_kernel<false><<<1024, 256, 0, stream>>>(x, xT, hiT, loT);
    norms_kernel<<<256, 256, 0, stream>>>(x, rnorm);
    gram_mfma_kernel<<<2048, 256, 0, stream>>>(hiT, loT, rnorm, pval, pidx, pval2);
    hipMemsetAsync(rcnt, 0, 4, stream);
    combine_kernel<<<64, 256, 0, stream>>>(pval, pidx, pval2, fidx, rcnt, ridx);
    if (use_xt) {
        rescue_kernel<true><<<64, 256, 0, stream>>>(xT, hiT, loT, rnorm, rcnt, ridx, fidx);
        fuse_kernel<true><<<256, 256, 0, stream>>>(x, xT, hiT, loT, W, fidx, out);
    } else {
        rescue_kernel<false><<<64, 256, 0, stream>>>(xT, hiT, loT, rnorm, rcnt, ridx, fidx);
        fuse_kernel<false><<<256, 256, 0, stream>>>(x, xT, hiT, loT, W, fidx, out);
    }
}

// Round 3
// 262.276 us; speedup vs baseline: 1.4443x; 1.0709x over previous
//
#include <hip/hip_runtime.h>
#include <hip/hip_bf16.h>
#include <math.h>

constexpr int B_ = 8;
constexpr int C_ = 256;
constexpr int N_ = 2048;
constexpr int CN_ = C_ * N_;        // 524288
constexpr int TOT_ = B_ * C_ * N_;  // 4194304

typedef __attribute__((ext_vector_type(8))) short bf16x8;
typedef __attribute__((ext_vector_type(4))) float f32x4;

__device__ __forceinline__ void g2l16(const void* g, void* l) {
    __builtin_amdgcn_global_load_lds(
        (const __attribute__((address_space(1))) void*)g,
        (__attribute__((address_space(3))) void*)l, 16, 0, 0);
}

__device__ __forceinline__ unsigned short bits(__hip_bfloat16 h) {
    union { __hip_bfloat16 b; unsigned short u; } cv;
    cv.b = h;
    return cv.u;
}

// ----------------------------------------- convert + norms (fused) ---------
// grid = B*32 = 256 blocks, 256 threads. Block: n-tile of 64 x all C=256.
// Produces xT[b][n][c] (fp32, optional), hiT/loT[b][n][c] (bf16 split), rnorm.
template <bool USE_XT>
__global__ __launch_bounds__(256) void convert_kernel(const float* __restrict__ x,
                                                      float* __restrict__ xT,
                                                      __hip_bfloat16* __restrict__ hiT,
                                                      __hip_bfloat16* __restrict__ loT,
                                                      float* __restrict__ rnorm) {
    const int batch = blockIdx.x >> 5;
    const int n0 = (blockIdx.x & 31) << 6;
    const int t = threadIdx.x;
    const int i = t & 63, j = t >> 6;

    __shared__ float tb[128][65];  // half of C at a time
    __shared__ float red[4][64];

    float s = 0.f;
    const float* xp = x + (size_t)batch * CN_ + n0 + i;

    for (int half = 0; half < 2; ++half) {
        const int cb = half << 7;
        __syncthreads();
#pragma unroll 8
        for (int r = 0; r < 32; ++r) {
            const int cl = j + r * 4;  // local c within half
            const float v = xp[(size_t)(cb + cl) * N_];
            tb[cl][i] = v;
            s += v * v;
        }
        __syncthreads();
        // write phase: 64 c-pairs x 64 n rows
        const int cp = t & 63;
        const int c2 = cp << 1;
        const int ng = t >> 6;  // 4 groups of 16 n
#pragma unroll 4
        for (int r = 0; r < 16; ++r) {
            const int n = ng * 16 + r;
            const float v0 = tb[c2][n], v1 = tb[c2 + 1][n];
            const size_t o = ((size_t)batch * N_ + n0 + n) * C_ + cb + c2;
            const __hip_bfloat16 h0 = __float2bfloat16(v0);
            const __hip_bfloat16 h1 = __float2bfloat16(v1);
            const float hf0 = __bfloat162float(h0), hf1 = __bfloat162float(h1);
            const __hip_bfloat16 g0 = __float2bfloat16(v0 - hf0);
            const __hip_bfloat16 g1 = __float2bfloat16(v1 - hf1);
            ((unsigned*)hiT)[o >> 1] = ((unsigned)bits(h1) << 16) | bits(h0);
            ((unsigned*)loT)[o >> 1] = ((unsigned)bits(g1) << 16) | bits(g0);
            if constexpr (USE_XT) {
                float2 fv;
                fv.x = v0;
                fv.y = v1;
                ((float2*)xT)[o >> 1] = fv;
            }
        }
    }
    red[j][i] = s;
    __syncthreads();
    if (j == 0) {
        const float tt = red[0][i] + red[1][i] + red[2][i] + red[3][i];
        rnorm[batch * N_ + n0 + i] = 1.0f / sqrtf(tt + 256.0f * 1e-6f);
    }
}

// ---------------------------------------------- gram (MFMA) + argmax -------
// grid = B*16*16 = 2048 blocks of 256 (4 waves). 128x128 output tile, BK=64.
// sim = hiT*hiT + hiT*loT + loT*hiT  (3 segments of K=256 each)
__global__ __launch_bounds__(256) void gram_mfma_kernel(
        const __hip_bfloat16* __restrict__ hiT, const __hip_bfloat16* __restrict__ loT,
        const float* __restrict__ rnorm,
        float* __restrict__ pval, int* __restrict__ pidx, float* __restrict__ pval2) {
    const int blk = blockIdx.x;
    const int bm = blk & 15;
    const int bn = (blk >> 4) & 15;
    const int batch = blk >> 8;
    const int n0 = bn << 7, m0 = bm << 7;

    __shared__ short As[128 * 64];  // [n-row][k 0..63], 128B rows, XOR-swizzled chunks
    __shared__ short Bs[128 * 64];
    __shared__ float rv1[128][2];
    __shared__ int ri1[128][2];
    __shared__ float rv2[128][2];

    const int tid = threadIdx.x;
    const int l = tid & 63, w = tid >> 6;
    const int lm = l & 15, q = l >> 4;
    const int wn = (w >> 1) << 6, wm = (w & 1) << 6;

    f32x4 acc[4][4];
#pragma unroll
    for (int rt = 0; rt < 4; ++rt)
#pragma unroll
        for (int ct = 0; ct < 4; ++ct) acc[rt][ct] = (f32x4){0.f, 0.f, 0.f, 0.f};

    const size_t bbase = (size_t)batch * CN_;

    for (int seg = 0; seg < 3; ++seg) {
        const __hip_bfloat16* Asrc = (seg == 2) ? loT : hiT;
        const __hip_bfloat16* Bsrc = (seg == 1) ? loT : hiT;
        for (int kt = 0; kt < 4; ++kt) {
            const int kb = kt << 6;
            __syncthreads();
#pragma unroll
            for (int p = 0; p < 4; ++p) {
                const int slot = tid + p * 256;
                const int r = slot >> 3, sidx = slot & 7;
                const int sw = sidx ^ (r & 7);  // XOR swizzle (self-inverse)
                g2l16(Asrc + bbase + (size_t)(n0 + r) * C_ + kb + sw * 8, As + slot * 8);
                g2l16(Bsrc + bbase + (size_t)(m0 + r) * C_ + kb + sw * 8, Bs + slot * 8);
            }
            __syncthreads();
#pragma unroll
            for (int kq = 0; kq < 2; ++kq) {
                bf16x8 af[4], bfr[4];
#pragma unroll
                for (int rt = 0; rt < 4; ++rt) {
                    const int row = wn + rt * 16 + lm;
                    af[rt] = *(const bf16x8*)(As + row * 64 + (((kq << 2) | q) ^ (lm & 7)) * 8);
                }
#pragma unroll
                for (int ct = 0; ct < 4; ++ct) {
                    const int row = wm + ct * 16 + lm;
                    bfr[ct] = *(const bf16x8*)(Bs + row * 64 + (((kq << 2) | q) ^ (lm & 7)) * 8);
                }
#pragma unroll
                for (int rt = 0; rt < 4; ++rt)
#pragma unroll
                    for (int ct = 0; ct < 4; ++ct)
                        acc[rt][ct] = __builtin_amdgcn_mfma_f32_16x16x32_bf16(
                            af[rt], bfr[ct], acc[rt][ct], 0, 0, 0);
            }
        }
    }

    // epilogue: scaled running argmax (best + second-best), diag excluded.
    float rn[4];
#pragma unroll
    for (int ct = 0; ct < 4; ++ct) rn[ct] = rnorm[batch * N_ + m0 + wm + ct * 16 + lm];

#pragma unroll
    for (int rt = 0; rt < 4; ++rt) {
#pragma unroll
        for (int r = 0; r < 4; ++r) {
            const int nrow = n0 + wn + rt * 16 + q * 4 + r;
            float v1 = -3.4e38f, v2 = -3.4e38f;
            int i1 = 0x7fffffff;
#pragma unroll
            for (int ct = 0; ct < 4; ++ct) {
                const int m = m0 + wm + ct * 16 + lm;
                const float v = acc[rt][ct][r] * rn[ct];
                if (m == nrow) continue;
                if (v > v1) { v2 = v1; v1 = v; i1 = m; }
                else if (v > v2) v2 = v;
            }
#pragma unroll
            for (int d = 1; d < 16; d <<= 1) {
                const float ov1 = __shfl_xor(v1, d, 64);
                const int oi1 = __shfl_xor(i1, d, 64);
                const float ov2 = __shfl_xor(v2, d, 64);
                if (ov1 > v1 || (ov1 == v1 && oi1 < i1)) {
                    v2 = fmaxf(v1, ov2); v1 = ov1; i1 = oi1;
                } else {
                    v2 = fmaxf(v2, ov1);
                }
            }
            if (lm == 0) {
                const int rloc = wn + rt * 16 + q * 4 + r;
                rv1[rloc][w & 1] = v1;
                ri1[rloc][w & 1] = i1;
                rv2[rloc][w & 1] = v2;
            }
        }
    }
    __syncthreads();
    if (tid < 128) {
        float v1 = rv1[tid][0]; int i1 = ri1[tid][0]; float v2 = rv2[tid][0];
        const float ov1 = rv1[tid][1]; const int oi1 = ri1[tid][1]; const float ov2 = rv2[tid][1];
        if (ov1 > v1 || (ov1 == v1 && oi1 < i1)) { v2 = fmaxf(v1, ov2); v1 = ov1; i1 = oi1; }
        else v2 = fmaxf(v2, ov1);
        const size_t gi = (size_t)(batch * 16 + bm) * N_ + n0 + tid;
        pval[gi] = v1; pidx[gi] = i1; pval2[gi] = v2;
    }
}

// -------------------------------------------------------------- combine ----
__global__ void combine_kernel(const float* __restrict__ pval, const int* __restrict__ pidx,
                               const float* __restrict__ pval2, int* __restrict__ fidx,
                               int* __restrict__ rcnt, int* __restrict__ ridx) {
    const int t = blockIdx.x * 256 + threadIdx.x;  // 16384
    const int batch = t >> 11, n = t & 2047;
    float v1 = -3.4e38f, v2 = -3.4e38f;
    int i1 = 0x7fffffff;
    for (int s = 0; s < 16; ++s) {
        const size_t gi = (size_t)(batch * 16 + s) * N_ + n;
        const float ov1 = pval[gi]; const int oi1 = pidx[gi]; const float ov2 = pval2[gi];
        if (ov1 > v1 || (ov1 == v1 && oi1 < i1)) { v2 = fmaxf(v1, ov2); v1 = ov1; i1 = oi1; }
        else v2 = fmaxf(v2, ov1);
    }
    fidx[t] = i1;
    if (v1 - v2 < 1e-4f) {
        const int slot = atomicAdd(rcnt, 1);
        ridx[slot] = t;
    }
}

// --------------------------------------------------------------- rescue ----
template <bool USE_XT>
__device__ __forceinline__ float loadT(const float* xT, const __hip_bfloat16* hiT,
                                       const __hip_bfloat16* loT, size_t idx) {
    if constexpr (USE_XT) return xT[idx];
    else return __bfloat162float(hiT[idx]) + __bfloat162float(loT[idx]);
}

template <bool USE_XT>
__global__ __launch_bounds__(256) void rescue_kernel(const float* __restrict__ xT,
                                                     const __hip_bfloat16* __restrict__ hiT,
                                                     const __hip_bfloat16* __restrict__ loT,
                                                     const float* __restrict__ rnorm,
                                                     const int* __restrict__ rcnt,
                                                     const int* __restrict__ ridx,
                                                     int* __restrict__ fidx) {
    const int cnt = *rcnt;
    const int tid = threadIdx.x;
    __shared__ float xrow[256];
    __shared__ float bv[256];
    __shared__ int bi[256];
    for (int rr = blockIdx.x; rr < cnt; rr += gridDim.x) {
        const int t = ridx[rr];
        const int batch = t >> 11, n = t & 2047;
        xrow[tid] = loadT<USE_XT>(xT, hiT, loT, ((size_t)batch * N_ + n) * C_ + tid);
        __syncthreads();
        float best = -3.4e38f;
        int besti = 0x7fffffff;
        for (int mm = tid; mm < N_; mm += 256) {
            const size_t mb = ((size_t)batch * N_ + mm) * C_;
            float s = 0.f;
            for (int c = 0; c < C_; ++c) s += xrow[c] * loadT<USE_XT>(xT, hiT, loT, mb + c);
            const float v = s * rnorm[batch * N_ + mm];
            if (mm != n && v > best) { best = v; besti = mm; }
        }
        bv[tid] = best; bi[tid] = besti;
        __syncthreads();
        for (int sft = 128; sft > 0; sft >>= 1) {
            if (tid < sft) {
                const float ov = bv[tid + sft]; const int oi = bi[tid + sft];
                if (ov > bv[tid] || (ov == bv[tid] && oi < bi[tid])) { bv[tid] = ov; bi[tid] = oi; }
            }
            __syncthreads();
        }
        if (tid == 0) fidx[t] = bi[0];
        __syncthreads();
    }
}

// ------------------------------------------------------ gate (softmax) -----
// grid = B*32 = 256 blocks, 1024 threads. Computes w0/w1 per (b, n).
template <bool USE_XT>
__global__ __launch_bounds__(1024) void gate_kernel(const float* __restrict__ x,
                                                    const float* __restrict__ xT,
                                                    const __hip_bfloat16* __restrict__ hiT,
                                                    const __hip_bfloat16* __restrict__ loT,
                                                    const float* __restrict__ W,
                                                    const int* __restrict__ fidx,
                                                    float2* __restrict__ w01) {
    const int batch = blockIdx.x >> 5;
    const int n0 = (blockIdx.x & 31) << 6;
    const int t = threadIdx.x;
    const int i = t & 63, j = t >> 6;  // j in 0..15, c-range j*16..+16

    __shared__ float Wl[1024];
    __shared__ int il[64];
    __shared__ float l0r[16][64], l1r[16][64];

    Wl[t] = W[t];
    if (t < 64) il[t] = fidx[batch * N_ + n0 + t];
    __syncthreads();

    const float* xb = x + (size_t)batch * CN_;
    const int myidx = il[i];
    const size_t tb = ((size_t)batch * N_ + myidx) * C_;

    float l0 = 0.f, l1 = 0.f;
    const int c0 = j * 16;
    if constexpr (USE_XT) {
        const float4* fr = (const float4*)(xT + tb + c0);
        float4 f4[4];
#pragma unroll
        for (int v = 0; v < 4; ++v) f4[v] = fr[v];
#pragma unroll
        for (int cc = 0; cc < 16; ++cc) {
            const int c = c0 + cc;
            const float xv = xb[(size_t)c * N_ + n0 + i];
            const float fv = ((const float*)f4)[cc];
            l0 += xv * Wl[c] + fv * Wl[256 + c];
            l1 += xv * Wl[512 + c] + fv * Wl[768 + c];
        }
    } else {
#pragma unroll
        for (int cc = 0; cc < 16; ++cc) {
            const int c = c0 + cc;
            const float xv = xb[(size_t)c * N_ + n0 + i];
            const float fv = loadT<false>(xT, hiT, loT, tb + c);
            l0 += xv * Wl[c] + fv * Wl[256 + c];
            l1 += xv * Wl[512 + c] + fv * Wl[768 + c];
        }
    }
    l0r[j][i] = l0;
    l1r[j][i] = l1;
    __syncthreads();
    if (t < 64) {
        float L0 = 0.f, L1 = 0.f;
#pragma unroll
        for (int g = 0; g < 16; ++g) { L0 += l0r[g][i]; L1 += l1r[g][i]; }
        const float mx = fmaxf(L0, L1);
        const float e0 = expf(L0 - mx);
        const float e1 = expf(L1 - mx);
        const float inv = 1.0f / (e0 + e1);
        float2 wv;
        wv.x = e0 * inv;
        wv.y = e1 * inv;
        w01[batch * N_ + n0 + i] = wv;
    }
}

// ------------------------------------------------- out (streaming) ---------
// grid = B * 32 ntiles * 8 csplits = 2048 blocks, 256 threads.
template <bool USE_XT>
__global__ __launch_bounds__(256) void out_kernel(const float* __restrict__ x,
                                                  const float* __restrict__ xT,
                                                  const __hip_bfloat16* __restrict__ hiT,
                                                  const __hip_bfloat16* __restrict__ loT,
                                                  const int* __restrict__ fidx,
                                                  const float2* __restrict__ w01,
                                                  float* __restrict__ out) {
    const int blk = blockIdx.x;
    const int cs = blk & 7;
    const int nt = (blk >> 3) & 31;
    const int batch = blk >> 8;
    const int n0 = nt << 6, c0 = cs << 5;
    const int t = threadIdx.x;
    const int i = t & 63, j = t >> 6;  // j: c-sub-octet 0..3
    const int n = n0 + i;

    const int myidx = fidx[batch * N_ + n];
    const float2 wv = w01[batch * N_ + n];
    const size_t tb = ((size_t)batch * N_ + myidx) * C_ + c0 + j * 8;

    float fvv[8];
    if constexpr (USE_XT) {
        const float4 f0 = *(const float4*)(xT + tb);
        const float4 f1 = *(const float4*)(xT + tb + 4);
#pragma unroll
        for (int e = 0; e < 4; ++e) { fvv[e] = f0[e]; fvv[4 + e] = f1[e]; }
    } else {
#pragma unroll
        for (int e = 0; e < 8; ++e) fvv[e] = loadT<false>(xT, hiT, loT, tb + e);
    }

#pragma unroll
    for (int e = 0; e < 8; ++e) {
        const int c = c0 + j * 8 + e;
        const size_t off = (size_t)batch * CN_ + (size_t)c * N_ + n;
        const float xv = x[off];
        const float fv = fvv[e];
        out[off] = xv * wv.x + fv * wv.y;
        out[TOT_ + off] = fv;
    }
}

// ---------------------------------------------------------------------------
extern "C" void kernel_launch(void* const* d_in, const int* in_sizes, int n_in,
                              void* d_out, int out_size, void* d_ws, size_t ws_size,
                              hipStream_t stream) {
    const float* x = (const float*)d_in[0];
    const float* W = (const float*)d_in[1];
    float* out = (float*)d_out;

    const size_t XT_BYTES = (size_t)TOT_ * 4;         // 16.78 MB
    const size_t BF_BYTES = (size_t)TOT_ * 2;         // 8.39 MB each
    const size_t NORM_BYTES = (size_t)B_ * N_ * 4;    // 64 KB
    const size_t P_BYTES = (size_t)B_ * 16 * N_ * 4;  // 1 MB each
    const size_t W01_BYTES = (size_t)B_ * N_ * 8;     // 128 KB
    const size_t need_lite = 2 * BF_BYTES + NORM_BYTES + 3 * P_BYTES +
                             2 * NORM_BYTES + 256 + W01_BYTES;
    const bool use_xt = (ws_size >= need_lite + XT_BYTES);

    uint8_t* p = (uint8_t*)d_ws;
    float* xT = nullptr;
    if (use_xt) { xT = (float*)p; p += XT_BYTES; }
    __hip_bfloat16* hiT = (__hip_bfloat16*)p; p += BF_BYTES;
    __hip_bfloat16* loT = (__hip_bfloat16*)p; p += BF_BYTES;
    float* rnorm = (float*)p; p += NORM_BYTES;
    float* pval = (float*)p; p += P_BYTES;
    int* pidx = (int*)p; p += P_BYTES;
    float* pval2 = (float*)p; p += P_BYTES;
    int* fidx = (int*)p; p += NORM_BYTES;
    int* rcnt = (int*)p; p += 256;
    int* ridx = (int*)p; p += NORM_BYTES;
    float2* w01 = (float2*)p; p += W01_BYTES;

    hipMemsetAsync(rcnt, 0, 4, stream);
    if (use_xt)
        convert_kernel<true><<<256, 256, 0, stream>>>(x, xT, hiT, loT, rnorm);
    else
        convert_kernel<false><<<256, 256, 0, stream>>>(x, xT, hiT, loT, rnorm);
    gram_mfma_kernel<<<2048, 256, 0, stream>>>(hiT, loT, rnorm, pval, pidx, pval2);
    combine_kernel<<<64, 256, 0, stream>>>(pval, pidx, pval2, fidx, rcnt, ridx);
    if (use_xt) {
        rescue_kernel<true><<<64, 256, 0, stream>>>(xT, hiT, loT, rnorm, rcnt, ridx, fidx);
        gate_kernel<true><<<256, 1024, 0, stream>>>(x, xT, hiT, loT, W, fidx, w01);
        out_kernel<true><<<2048, 256, 0, stream>>>(x, xT, hiT, loT, fidx, w01, out);
    } else {
        rescue_kernel<false><<<64, 256, 0, stream>>>(xT, hiT, loT, rnorm, rcnt, ridx, fidx);
        gate_kernel<false><<<256, 1024, 0, stream>>>(x, xT, hiT, loT, W, fidx, w01);
        out_kernel<false><<<2048, 256, 0, stream>>>(x, xT, hiT, loT, fidx, w01, out);
    }
}

// Round 4
// 259.424 us; speedup vs baseline: 1.4602x; 1.0110x over previous
//
#include <hip/hip_runtime.h>
#include <hip/hip_bf16.h>
#include <math.h>

constexpr int B_ = 8;
constexpr int C_ = 256;
constexpr int N_ = 2048;
constexpr int CN_ = C_ * N_;        // 524288
constexpr int TOT_ = B_ * C_ * N_;  // 4194304
constexpr int NTILES = 16;          // 128-wide strips
constexpr int NPAIRS = 136;         // triangular tiles per batch

typedef __attribute__((ext_vector_type(8))) short bf16x8;
typedef __attribute__((ext_vector_type(4))) float f32x4;

__device__ __forceinline__ void g2l16(const void* g, void* l) {
    __builtin_amdgcn_global_load_lds(
        (const __attribute__((address_space(1))) void*)g,
        (__attribute__((address_space(3))) void*)l, 16, 0, 0);
}

__device__ __forceinline__ unsigned short bits(__hip_bfloat16 h) {
    union { __hip_bfloat16 b; unsigned short u; } cv;
    cv.b = h;
    return cv.u;
}

// ----------------------------------------- convert (+ partial norms) -------
// grid = 8 batches x 4 ctiles x 32 ntiles = 1024 blocks, 256 threads.
// 64c x 64n tile: transpose, bf16 hi/lo split, optional xT, atomic norm part.
template <bool USE_XT>
__global__ __launch_bounds__(256) void convert_kernel(const float* __restrict__ x,
                                                      float* __restrict__ xT,
                                                      __hip_bfloat16* __restrict__ hiT,
                                                      __hip_bfloat16* __restrict__ loT,
                                                      float* __restrict__ normacc) {
    const int blk = blockIdx.x;
    const int nt = blk & 31, ctile = (blk >> 5) & 3, batch = blk >> 7;
    const int n0 = nt << 6, c0 = ctile << 6;
    const int t = threadIdx.x;
    const int i = t & 63, j = t >> 6;

    __shared__ float tb[64][65];
    __shared__ float red[4][64];

    float s = 0.f;
    const float* xp = x + (size_t)batch * CN_ + (size_t)c0 * N_ + n0 + i;
#pragma unroll 4
    for (int r = 0; r < 16; ++r) {
        const int cl = j + r * 4;
        const float v = xp[(size_t)cl * N_];
        tb[cl][i] = v;
        s += v * v;
    }
    red[j][i] = s;
    __syncthreads();

    const int cp = t & 31;  // c-pair
    const int c2 = cp << 1;
    const int nb = t >> 5;  // 8 n-groups
#pragma unroll 4
    for (int r = 0; r < 8; ++r) {
        const int n = nb + r * 8;
        const float v0 = tb[c2][n], v1 = tb[c2 + 1][n];
        const size_t o = ((size_t)batch * N_ + n0 + n) * C_ + c0 + c2;
        const __hip_bfloat16 h0 = __float2bfloat16(v0);
        const __hip_bfloat16 h1 = __float2bfloat16(v1);
        const __hip_bfloat16 g0 = __float2bfloat16(v0 - __bfloat162float(h0));
        const __hip_bfloat16 g1 = __float2bfloat16(v1 - __bfloat162float(h1));
        ((unsigned*)hiT)[o >> 1] = ((unsigned)bits(h1) << 16) | bits(h0);
        ((unsigned*)loT)[o >> 1] = ((unsigned)bits(g1) << 16) | bits(g0);
        if constexpr (USE_XT) {
            float2 fv;
            fv.x = v0;
            fv.y = v1;
            ((float2*)xT)[o >> 1] = fv;
        }
    }
    if (j == 0) {
        const float tt = red[0][i] + red[1][i] + red[2][i] + red[3][i];
        atomicAdd(normacc + batch * N_ + n0 + i, tt);
    }
}

__global__ void rnorm_fin_kernel(const float* __restrict__ normacc,
                                 float* __restrict__ rnorm) {
    const int t = blockIdx.x * 256 + threadIdx.x;  // 16384
    rnorm[t] = 1.0f / sqrtf(normacc[t] + 256.0f * 1e-6f);
}

// ------------------------------- gram (MFMA, triangular) + argmax ----------
// grid = B * 136 blocks of 256 (4 waves). 128x128 tile, BK=64, bn<=bm.
// sim = hiT*hiT + hiT*loT + loT*hiT. Off-diag blocks emit row AND col argmax.
__global__ __launch_bounds__(256) void gram_mfma_kernel(
        const __hip_bfloat16* __restrict__ hiT, const __hip_bfloat16* __restrict__ loT,
        const float* __restrict__ rnorm,
        float* __restrict__ pval, int* __restrict__ pidx, float* __restrict__ pval2) {
    const int blk = blockIdx.x;
    const int batch = blk / NPAIRS;
    int p = blk - batch * NPAIRS;
    int bn = 0;
    while (p >= NTILES - bn) { p -= NTILES - bn; ++bn; }
    const int bm = bn + p;
    const bool diag = (bn == bm);
    const int n0 = bn << 7, m0 = bm << 7;

    __shared__ short As[128 * 64];
    __shared__ short Bs[128 * 64];
    __shared__ float rv1[128][2];
    __shared__ int ri1[128][2];
    __shared__ float rv2[128][2];
    __shared__ float cv1[128][2];
    __shared__ int ci1[128][2];
    __shared__ float cv2[128][2];
    __shared__ float rnA[128];

    const int tid = threadIdx.x;
    const int l = tid & 63, w = tid >> 6;
    const int lm = l & 15, q = l >> 4;
    const int wn = (w >> 1) << 6, wm = (w & 1) << 6;

    f32x4 acc[4][4];
#pragma unroll
    for (int rt = 0; rt < 4; ++rt)
#pragma unroll
        for (int ct = 0; ct < 4; ++ct) acc[rt][ct] = (f32x4){0.f, 0.f, 0.f, 0.f};

    const size_t bbase = (size_t)batch * CN_;

    for (int seg = 0; seg < 3; ++seg) {
        const __hip_bfloat16* Asrc = (seg == 2) ? loT : hiT;
        const __hip_bfloat16* Bsrc = (seg == 1) ? loT : hiT;
        for (int kt = 0; kt < 4; ++kt) {
            const int kb = kt << 6;
            __syncthreads();
#pragma unroll
            for (int pp = 0; pp < 4; ++pp) {
                const int slot = tid + pp * 256;
                const int r = slot >> 3, sidx = slot & 7;
                const int sw = sidx ^ (r & 7);  // XOR swizzle (self-inverse)
                g2l16(Asrc + bbase + (size_t)(n0 + r) * C_ + kb + sw * 8, As + slot * 8);
                g2l16(Bsrc + bbase + (size_t)(m0 + r) * C_ + kb + sw * 8, Bs + slot * 8);
            }
            __syncthreads();
#pragma unroll
            for (int kq = 0; kq < 2; ++kq) {
                bf16x8 af[4], bfr[4];
#pragma unroll
                for (int rt = 0; rt < 4; ++rt) {
                    const int row = wn + rt * 16 + lm;
                    af[rt] = *(const bf16x8*)(As + row * 64 + (((kq << 2) | q) ^ (lm & 7)) * 8);
                }
#pragma unroll
                for (int ct = 0; ct < 4; ++ct) {
                    const int row = wm + ct * 16 + lm;
                    bfr[ct] = *(const bf16x8*)(Bs + row * 64 + (((kq << 2) | q) ^ (lm & 7)) * 8);
                }
#pragma unroll
                for (int rt = 0; rt < 4; ++rt)
#pragma unroll
                    for (int ct = 0; ct < 4; ++ct)
                        acc[rt][ct] = __builtin_amdgcn_mfma_f32_16x16x32_bf16(
                            af[rt], bfr[ct], acc[rt][ct], 0, 0, 0);
            }
        }
    }

    // stage n-strip rnorms for the col path
    if (tid < 128) rnA[tid] = rnorm[batch * N_ + n0 + tid];
    __syncthreads();

    // ---- row path: for rows n (n-strip), candidates m (m-strip), scale rnorm[m]
    float rnm[4];
#pragma unroll
    for (int ct = 0; ct < 4; ++ct) rnm[ct] = rnorm[batch * N_ + m0 + wm + ct * 16 + lm];

#pragma unroll
    for (int rt = 0; rt < 4; ++rt) {
#pragma unroll
        for (int r = 0; r < 4; ++r) {
            const int nrow = n0 + wn + rt * 16 + q * 4 + r;
            float v1 = -3.4e38f, v2 = -3.4e38f;
            int i1 = 0x7fffffff;
#pragma unroll
            for (int ct = 0; ct < 4; ++ct) {
                const int m = m0 + wm + ct * 16 + lm;
                const float v = acc[rt][ct][r] * rnm[ct];
                if (m == nrow) continue;
                if (v > v1) { v2 = v1; v1 = v; i1 = m; }
                else if (v > v2) v2 = v;
            }
#pragma unroll
            for (int d = 1; d < 16; d <<= 1) {
                const float ov1 = __shfl_xor(v1, d, 64);
                const int oi1 = __shfl_xor(i1, d, 64);
                const float ov2 = __shfl_xor(v2, d, 64);
                if (ov1 > v1 || (ov1 == v1 && oi1 < i1)) {
                    v2 = fmaxf(v1, ov2); v1 = ov1; i1 = oi1;
                } else {
                    v2 = fmaxf(v2, ov1);
                }
            }
            if (lm == 0) {
                const int rloc = wn + rt * 16 + q * 4 + r;
                rv1[rloc][w & 1] = v1;
                ri1[rloc][w & 1] = i1;
                rv2[rloc][w & 1] = v2;
            }
        }
    }

    // ---- col path: for rows m (m-strip), candidates n (n-strip), scale rnorm[n]
    if (!diag) {
        float rnn[4][4];
#pragma unroll
        for (int rt = 0; rt < 4; ++rt)
#pragma unroll
            for (int r = 0; r < 4; ++r) rnn[rt][r] = rnA[wn + rt * 16 + q * 4 + r];
#pragma unroll
        for (int ct = 0; ct < 4; ++ct) {
            float v1 = -3.4e38f, v2 = -3.4e38f;
            int i1 = 0x7fffffff;
#pragma unroll
            for (int rt = 0; rt < 4; ++rt) {
#pragma unroll
                for (int r = 0; r < 4; ++r) {
                    const float v = acc[rt][ct][r] * rnn[rt][r];
                    const int nn = n0 + wn + rt * 16 + q * 4 + r;
                    if (v > v1) { v2 = v1; v1 = v; i1 = nn; }
                    else if (v > v2) v2 = v;
                }
            }
#pragma unroll
            for (int d = 16; d < 64; d <<= 1) {
                const float ov1 = __shfl_xor(v1, d, 64);
                const int oi1 = __shfl_xor(i1, d, 64);
                const float ov2 = __shfl_xor(v2, d, 64);
                if (ov1 > v1 || (ov1 == v1 && oi1 < i1)) {
                    v2 = fmaxf(v1, ov2); v1 = ov1; i1 = oi1;
                } else {
                    v2 = fmaxf(v2, ov1);
                }
            }
            if (q == 0) {
                const int mloc = wm + ct * 16 + lm;
                cv1[mloc][w >> 1] = v1;
                ci1[mloc][w >> 1] = i1;
                cv2[mloc][w >> 1] = v2;
            }
        }
    }
    __syncthreads();

    if (tid < 128) {
        // row result -> slot bm, rows n-strip
        {
            float v1 = rv1[tid][0]; int i1 = ri1[tid][0]; float v2 = rv2[tid][0];
            const float ov1 = rv1[tid][1]; const int oi1 = ri1[tid][1]; const float ov2 = rv2[tid][1];
            if (ov1 > v1 || (ov1 == v1 && oi1 < i1)) { v2 = fmaxf(v1, ov2); v1 = ov1; i1 = oi1; }
            else v2 = fmaxf(v2, ov1);
            const size_t gi = (size_t)(batch * NTILES + bm) * N_ + n0 + tid;
            pval[gi] = v1; pidx[gi] = i1; pval2[gi] = v2;
        }
        // col result -> slot bn, rows m-strip
        if (!diag) {
            float v1 = cv1[tid][0]; int i1 = ci1[tid][0]; float v2 = cv2[tid][0];
            const float ov1 = cv1[tid][1]; const int oi1 = ci1[tid][1]; const float ov2 = cv2[tid][1];
            if (ov1 > v1 || (ov1 == v1 && oi1 < i1)) { v2 = fmaxf(v1, ov2); v1 = ov1; i1 = oi1; }
            else v2 = fmaxf(v2, ov1);
            const size_t gi = (size_t)(batch * NTILES + bn) * N_ + m0 + tid;
            pval[gi] = v1; pidx[gi] = i1; pval2[gi] = v2;
        }
    }
}

// -------------------------------------------------------------- combine ----
__global__ void combine_kernel(const float* __restrict__ pval, const int* __restrict__ pidx,
                               const float* __restrict__ pval2, int* __restrict__ fidx,
                               int* __restrict__ rcnt, int* __restrict__ ridx) {
    const int t = blockIdx.x * 256 + threadIdx.x;  // 16384
    const int batch = t >> 11, n = t & 2047;
    float v1 = -3.4e38f, v2 = -3.4e38f;
    int i1 = 0x7fffffff;
    for (int s = 0; s < NTILES; ++s) {
        const size_t gi = (size_t)(batch * NTILES + s) * N_ + n;
        const float ov1 = pval[gi]; const int oi1 = pidx[gi]; const float ov2 = pval2[gi];
        if (ov1 > v1 || (ov1 == v1 && oi1 < i1)) { v2 = fmaxf(v1, ov2); v1 = ov1; i1 = oi1; }
        else v2 = fmaxf(v2, ov1);
    }
    fidx[t] = i1;
    if (v1 - v2 < 1e-4f) {
        const int slot = atomicAdd(rcnt, 1);
        ridx[slot] = t;
    }
}

// --------------------------------------------------------------- rescue ----
template <bool USE_XT>
__device__ __forceinline__ float loadT(const float* xT, const __hip_bfloat16* hiT,
                                       const __hip_bfloat16* loT, size_t idx) {
    if constexpr (USE_XT) return xT[idx];
    else return __bfloat162float(hiT[idx]) + __bfloat162float(loT[idx]);
}

template <bool USE_XT>
__global__ __launch_bounds__(256) void rescue_kernel(const float* __restrict__ xT,
                                                     const __hip_bfloat16* __restrict__ hiT,
                                                     const __hip_bfloat16* __restrict__ loT,
                                                     const float* __restrict__ rnorm,
                                                     const int* __restrict__ rcnt,
                                                     const int* __restrict__ ridx,
                                                     int* __restrict__ fidx) {
    const int cnt = *rcnt;
    const int tid = threadIdx.x;
    __shared__ float xrow[256];
    __shared__ float bv[256];
    __shared__ int bi[256];
    for (int rr = blockIdx.x; rr < cnt; rr += gridDim.x) {
        const int t = ridx[rr];
        const int batch = t >> 11, n = t & 2047;
        xrow[tid] = loadT<USE_XT>(xT, hiT, loT, ((size_t)batch * N_ + n) * C_ + tid);
        __syncthreads();
        float best = -3.4e38f;
        int besti = 0x7fffffff;
        for (int mm = tid; mm < N_; mm += 256) {
            const size_t mb = ((size_t)batch * N_ + mm) * C_;
            float s = 0.f;
            for (int c = 0; c < C_; ++c) s += xrow[c] * loadT<USE_XT>(xT, hiT, loT, mb + c);
            const float v = s * rnorm[batch * N_ + mm];
            if (mm != n && v > best) { best = v; besti = mm; }
        }
        bv[tid] = best; bi[tid] = besti;
        __syncthreads();
        for (int sft = 128; sft > 0; sft >>= 1) {
            if (tid < sft) {
                const float ov = bv[tid + sft]; const int oi = bi[tid + sft];
                if (ov > bv[tid] || (ov == bv[tid] && oi < bi[tid])) { bv[tid] = ov; bi[tid] = oi; }
            }
            __syncthreads();
        }
        if (tid == 0) fidx[t] = bi[0];
        __syncthreads();
    }
}

// ------------------------------------------------------ gate (softmax) -----
// grid = 1024 blocks, 256 threads; 16 n per block.
template <bool USE_XT>
__global__ __launch_bounds__(256) void gate_kernel(const float* __restrict__ x,
                                                   const float* __restrict__ xT,
                                                   const __hip_bfloat16* __restrict__ hiT,
                                                   const __hip_bfloat16* __restrict__ loT,
                                                   const float* __restrict__ W,
                                                   const int* __restrict__ fidx,
                                                   float2* __restrict__ w01) {
    const int batch = blockIdx.x >> 7;
    const int n0 = (blockIdx.x & 127) << 4;
    const int t = threadIdx.x;
    const int i = t & 15, j = t >> 4;  // j in 0..15, c-range j*16..+16

    __shared__ float Wl[1024];
    __shared__ int il[16];
    __shared__ float l0r[16][17], l1r[16][17];

    for (int u = t; u < 1024; u += 256) Wl[u] = W[u];
    if (t < 16) il[t] = fidx[batch * N_ + n0 + t];
    __syncthreads();

    const float* xb = x + (size_t)batch * CN_;
    const int myidx = il[i];
    const size_t tb = ((size_t)batch * N_ + myidx) * C_;

    float l0 = 0.f, l1 = 0.f;
    const int c0 = j * 16;
    if constexpr (USE_XT) {
        const float4* fr = (const float4*)(xT + tb + c0);
        float4 f4[4];
#pragma unroll
        for (int v = 0; v < 4; ++v) f4[v] = fr[v];
#pragma unroll
        for (int cc = 0; cc < 16; ++cc) {
            const int c = c0 + cc;
            const float xv = xb[(size_t)c * N_ + n0 + i];
            const float fv = ((const float*)f4)[cc];
            l0 += xv * Wl[c] + fv * Wl[256 + c];
            l1 += xv * Wl[512 + c] + fv * Wl[768 + c];
        }
    } else {
#pragma unroll
        for (int cc = 0; cc < 16; ++cc) {
            const int c = c0 + cc;
            const float xv = xb[(size_t)c * N_ + n0 + i];
            const float fv = loadT<false>(xT, hiT, loT, tb + c);
            l0 += xv * Wl[c] + fv * Wl[256 + c];
            l1 += xv * Wl[512 + c] + fv * Wl[768 + c];
        }
    }
    l0r[j][i] = l0;
    l1r[j][i] = l1;
    __syncthreads();
    if (t < 16) {
        float L0 = 0.f, L1 = 0.f;
#pragma unroll
        for (int g = 0; g < 16; ++g) { L0 += l0r[g][i]; L1 += l1r[g][i]; }
        const float mx = fmaxf(L0, L1);
        const float e0 = expf(L0 - mx);
        const float e1 = expf(L1 - mx);
        const float inv = 1.0f / (e0 + e1);
        float2 wv;
        wv.x = e0 * inv;
        wv.y = e1 * inv;
        w01[batch * N_ + n0 + i] = wv;
    }
}

// ------------------------------------------------- out (streaming) ---------
// grid = B * 32 ntiles * 8 csplits = 2048 blocks, 256 threads.
template <bool USE_XT>
__global__ __launch_bounds__(256) void out_kernel(const float* __restrict__ x,
                                                  const float* __restrict__ xT,
                                                  const __hip_bfloat16* __restrict__ hiT,
                                                  const __hip_bfloat16* __restrict__ loT,
                                                  const int* __restrict__ fidx,
                                                  const float2* __restrict__ w01,
                                                  float* __restrict__ out) {
    const int blk = blockIdx.x;
    const int cs = blk & 7;
    const int nt = (blk >> 3) & 31;
    const int batch = blk >> 8;
    const int n0 = nt << 6, c0 = cs << 5;
    const int t = threadIdx.x;
    const int i = t & 63, j = t >> 6;
    const int n = n0 + i;

    const int myidx = fidx[batch * N_ + n];
    const float2 wv = w01[batch * N_ + n];
    const size_t tb = ((size_t)batch * N_ + myidx) * C_ + c0 + j * 8;

    float fvv[8];
    if constexpr (USE_XT) {
        const float4 f0 = *(const float4*)(xT + tb);
        const float4 f1 = *(const float4*)(xT + tb + 4);
#pragma unroll
        for (int e = 0; e < 4; ++e) { fvv[e] = f0[e]; fvv[4 + e] = f1[e]; }
    } else {
#pragma unroll
        for (int e = 0; e < 8; ++e) fvv[e] = loadT<false>(xT, hiT, loT, tb + e);
    }

#pragma unroll
    for (int e = 0; e < 8; ++e) {
        const int c = c0 + j * 8 + e;
        const size_t off = (size_t)batch * CN_ + (size_t)c * N_ + n;
        const float xv = x[off];
        const float fv = fvv[e];
        out[off] = xv * wv.x + fv * wv.y;
        out[TOT_ + off] = fv;
    }
}

// ---------------------------------------------------------------------------
extern "C" void kernel_launch(void* const* d_in, const int* in_sizes, int n_in,
                              void* d_out, int out_size, void* d_ws, size_t ws_size,
                              hipStream_t stream) {
    const float* x = (const float*)d_in[0];
    const float* W = (const float*)d_in[1];
    float* out = (float*)d_out;

    const size_t XT_BYTES = (size_t)TOT_ * 4;             // 16.78 MB
    const size_t BF_BYTES = (size_t)TOT_ * 2;             // 8.39 MB each
    const size_t NORM_BYTES = (size_t)B_ * N_ * 4;        // 64 KB
    const size_t P_BYTES = (size_t)B_ * NTILES * N_ * 4;  // 1 MB each
    const size_t W01_BYTES = (size_t)B_ * N_ * 8;         // 128 KB
    const size_t need_lite = 2 * BF_BYTES + 2 * NORM_BYTES + 3 * P_BYTES +
                             2 * NORM_BYTES + 256 + W01_BYTES;
    const bool use_xt = (ws_size >= need_lite + XT_BYTES);

    uint8_t* p = (uint8_t*)d_ws;
    float* xT = nullptr;
    if (use_xt) { xT = (float*)p; p += XT_BYTES; }
    __hip_bfloat16* hiT = (__hip_bfloat16*)p; p += BF_BYTES;
    __hip_bfloat16* loT = (__hip_bfloat16*)p; p += BF_BYTES;
    float* rnorm = (float*)p; p += NORM_BYTES;
    float* normacc = (float*)p; p += NORM_BYTES;
    float* pval = (float*)p; p += P_BYTES;
    int* pidx = (int*)p; p += P_BYTES;
    float* pval2 = (float*)p; p += P_BYTES;
    int* fidx = (int*)p; p += NORM_BYTES;
    int* rcnt = (int*)p; p += 256;
    int* ridx = (int*)p; p += NORM_BYTES;
    float2* w01 = (float2*)p; p += W01_BYTES;

    hipMemsetAsync(rcnt, 0, 4, stream);
    hipMemsetAsync(normacc, 0, NORM_BYTES, stream);
    if (use_xt)
        convert_kernel<true><<<1024, 256, 0, stream>>>(x, xT, hiT, loT, normacc);
    else
        convert_kernel<false><<<1024, 256, 0, stream>>>(x, xT, hiT, loT, normacc);
    rnorm_fin_kernel<<<64, 256, 0, stream>>>(normacc, rnorm);
    gram_mfma_kernel<<<B_ * NPAIRS, 256, 0, stream>>>(hiT, loT, rnorm, pval, pidx, pval2);
    combine_kernel<<<64, 256, 0, stream>>>(pval, pidx, pval2, fidx, rcnt, ridx);
    if (use_xt) {
        rescue_kernel<true><<<64, 256, 0, stream>>>(xT, hiT, loT, rnorm, rcnt, ridx, fidx);
        gate_kernel<true><<<1024, 256, 0, stream>>>(x, xT, hiT, loT, W, fidx, w01);
        out_kernel<true><<<2048, 256, 0, stream>>>(x, xT, hiT, loT, fidx, w01, out);
    } else {
        rescue_kernel<false><<<64, 256, 0, stream>>>(xT, hiT, loT, rnorm, rcnt, ridx, fidx);
        gate_kernel<false><<<1024, 256, 0, stream>>>(x, xT, hiT, loT, W, fidx, w01);
        out_kernel<false><<<2048, 256, 0, stream>>>(x, xT, hiT, loT, fidx, w01, out);
    }
}

// Round 5
// 207.336 us; speedup vs baseline: 1.8271x; 1.2512x over previous
//
#include <hip/hip_runtime.h>
#include <hip/hip_bf16.h>
#include <math.h>

constexpr int B_ = 8;
constexpr int C_ = 256;
constexpr int N_ = 2048;
constexpr int CN_ = C_ * N_;        // 524288
constexpr int TOT_ = B_ * C_ * N_;  // 4194304
constexpr int NTILES = 16;          // 128-wide strips
constexpr int NPAIRS = 136;         // triangular tiles per batch

typedef __attribute__((ext_vector_type(8))) short bf16x8;
typedef __attribute__((ext_vector_type(4))) float f32x4;

__device__ __forceinline__ void g2l16(const void* g, void* l) {
    __builtin_amdgcn_global_load_lds(
        (const __attribute__((address_space(1))) void*)g,
        (__attribute__((address_space(3))) void*)l, 16, 0, 0);
}

__device__ __forceinline__ unsigned short bits(__hip_bfloat16 h) {
    union { __hip_bfloat16 b; unsigned short u; } cv;
    cv.b = h;
    return cv.u;
}

__device__ __forceinline__ float b2f(short s) {
    union { float f; unsigned u; } cv;
    cv.u = ((unsigned)(unsigned short)s) << 16;
    return cv.f;
}

// ----------------------------------------- convert (+ partial norms) -------
// grid = 1024 blocks (batch = blk&7 -> XCD-local), 256 threads.
// 64c x 64n tile: transpose, bf16 hi/lo split, atomic norm partial.
__global__ __launch_bounds__(256) void convert_kernel(const float* __restrict__ x,
                                                      __hip_bfloat16* __restrict__ hiT,
                                                      __hip_bfloat16* __restrict__ loT,
                                                      float* __restrict__ normacc) {
    const int blk = blockIdx.x;
    const int batch = blk & 7;
    const int nt = (blk >> 3) & 31;
    const int ctile = blk >> 8;
    const int n0 = nt << 6, c0 = ctile << 6;
    const int t = threadIdx.x;
    const int i = t & 63, j = t >> 6;

    __shared__ float tb[64][65];
    __shared__ float red[4][64];

    float s = 0.f;
    const float* xp = x + (size_t)batch * CN_ + (size_t)c0 * N_ + n0 + i;
#pragma unroll 4
    for (int r = 0; r < 16; ++r) {
        const int cl = j + r * 4;
        const float v = xp[(size_t)cl * N_];
        tb[cl][i] = v;
        s += v * v;
    }
    red[j][i] = s;
    __syncthreads();

    const int cp = t & 31;  // c-pair
    const int c2 = cp << 1;
    const int nb = t >> 5;  // 8 n-groups
#pragma unroll 4
    for (int r = 0; r < 8; ++r) {
        const int n = nb + r * 8;
        const float v0 = tb[c2][n], v1 = tb[c2 + 1][n];
        const size_t o = ((size_t)batch * N_ + n0 + n) * C_ + c0 + c2;
        const __hip_bfloat16 h0 = __float2bfloat16(v0);
        const __hip_bfloat16 h1 = __float2bfloat16(v1);
        const __hip_bfloat16 g0 = __float2bfloat16(v0 - __bfloat162float(h0));
        const __hip_bfloat16 g1 = __float2bfloat16(v1 - __bfloat162float(h1));
        ((unsigned*)hiT)[o >> 1] = ((unsigned)bits(h1) << 16) | bits(h0);
        ((unsigned*)loT)[o >> 1] = ((unsigned)bits(g1) << 16) | bits(g0);
    }
    if (j == 0) {
        const float tt = red[0][i] + red[1][i] + red[2][i] + red[3][i];
        atomicAdd(normacc + batch * N_ + n0 + i, tt);
    }
}

__global__ void rnorm_fin_kernel(const float* __restrict__ normacc,
                                 float* __restrict__ rnorm) {
    const int t = blockIdx.x * 256 + threadIdx.x;  // 16384
    rnorm[t] = 1.0f / sqrtf(normacc[t] + 256.0f * 1e-6f);
}

// ------------------------------- gram (MFMA, triangular) + argmax ----------
// grid = B * 136 blocks of 256 (4 waves); batch = blk & 7 (XCD-local L2).
// 128x128 tile, BK=64, bn<=bm. sim = hi*hi + hi*lo + lo*hi.
// Off-diag blocks emit row AND col argmax. Epilogue arrays overlay As (LDS=32KB).
__global__ __launch_bounds__(256) void gram_mfma_kernel(
        const __hip_bfloat16* __restrict__ hiT, const __hip_bfloat16* __restrict__ loT,
        const float* __restrict__ rnorm,
        float* __restrict__ pval, int* __restrict__ pidx, float* __restrict__ pval2) {
    const int blk = blockIdx.x;
    const int batch = blk & 7;
    int p = blk >> 3;  // 0..135
    int bn = 0;
    while (p >= NTILES - bn) { p -= NTILES - bn; ++bn; }
    const int bm = bn + p;
    const bool diag = (bn == bm);
    const int n0 = bn << 7, m0 = bm << 7;

    __shared__ short As[128 * 64];
    __shared__ short Bs[128 * 64];
    // epilogue arrays overlaid on As (safe: only used after post-K-loop barrier)
    float (*rv1)[2] = (float(*)[2])(As + 0);
    int (*ri1)[2] = (int(*)[2])(As + 512);
    float (*rv2)[2] = (float(*)[2])(As + 1024);
    float (*cv1)[2] = (float(*)[2])(As + 1536);
    int (*ci1)[2] = (int(*)[2])(As + 2048);
    float (*cv2)[2] = (float(*)[2])(As + 2560);
    float* rnA = (float*)(As + 3072);

    const int tid = threadIdx.x;
    const int l = tid & 63, w = tid >> 6;
    const int lm = l & 15, q = l >> 4;
    const int wn = (w >> 1) << 6, wm = (w & 1) << 6;

    f32x4 acc[4][4];
#pragma unroll
    for (int rt = 0; rt < 4; ++rt)
#pragma unroll
        for (int ct = 0; ct < 4; ++ct) acc[rt][ct] = (f32x4){0.f, 0.f, 0.f, 0.f};

    const size_t bbase = (size_t)batch * CN_;

    for (int seg = 0; seg < 3; ++seg) {
        const __hip_bfloat16* Asrc = (seg == 2) ? loT : hiT;
        const __hip_bfloat16* Bsrc = (seg == 1) ? loT : hiT;
        for (int kt = 0; kt < 4; ++kt) {
            const int kb = kt << 6;
            __syncthreads();
#pragma unroll
            for (int pp = 0; pp < 4; ++pp) {
                const int slot = tid + pp * 256;
                const int r = slot >> 3, sidx = slot & 7;
                const int sw = sidx ^ (r & 7);  // XOR swizzle (self-inverse)
                g2l16(Asrc + bbase + (size_t)(n0 + r) * C_ + kb + sw * 8, As + slot * 8);
                g2l16(Bsrc + bbase + (size_t)(m0 + r) * C_ + kb + sw * 8, Bs + slot * 8);
            }
            __syncthreads();
#pragma unroll
            for (int kq = 0; kq < 2; ++kq) {
                bf16x8 af[4], bfr[4];
#pragma unroll
                for (int rt = 0; rt < 4; ++rt) {
                    const int row = wn + rt * 16 + lm;
                    af[rt] = *(const bf16x8*)(As + row * 64 + (((kq << 2) | q) ^ (lm & 7)) * 8);
                }
#pragma unroll
                for (int ct = 0; ct < 4; ++ct) {
                    const int row = wm + ct * 16 + lm;
                    bfr[ct] = *(const bf16x8*)(Bs + row * 64 + (((kq << 2) | q) ^ (lm & 7)) * 8);
                }
#pragma unroll
                for (int rt = 0; rt < 4; ++rt)
#pragma unroll
                    for (int ct = 0; ct < 4; ++ct)
                        acc[rt][ct] = __builtin_amdgcn_mfma_f32_16x16x32_bf16(
                            af[rt], bfr[ct], acc[rt][ct], 0, 0, 0);
            }
        }
    }

    __syncthreads();  // drain all LDS reads before overlaying As with epilogue data
    if (tid < 128) rnA[tid] = rnorm[batch * N_ + n0 + tid];

    // ---- row path: rows n (n-strip), candidates m (m-strip), scale rnorm[m]
    float rnm[4];
#pragma unroll
    for (int ct = 0; ct < 4; ++ct) rnm[ct] = rnorm[batch * N_ + m0 + wm + ct * 16 + lm];

#pragma unroll
    for (int rt = 0; rt < 4; ++rt) {
#pragma unroll
        for (int r = 0; r < 4; ++r) {
            const int nrow = n0 + wn + rt * 16 + q * 4 + r;
            float v1 = -3.4e38f, v2 = -3.4e38f;
            int i1 = 0x7fffffff;
#pragma unroll
            for (int ct = 0; ct < 4; ++ct) {
                const int m = m0 + wm + ct * 16 + lm;
                const float v = acc[rt][ct][r] * rnm[ct];
                if (m == nrow) continue;
                if (v > v1) { v2 = v1; v1 = v; i1 = m; }
                else if (v > v2) v2 = v;
            }
#pragma unroll
            for (int d = 1; d < 16; d <<= 1) {
                const float ov1 = __shfl_xor(v1, d, 64);
                const int oi1 = __shfl_xor(i1, d, 64);
                const float ov2 = __shfl_xor(v2, d, 64);
                if (ov1 > v1 || (ov1 == v1 && oi1 < i1)) {
                    v2 = fmaxf(v1, ov2); v1 = ov1; i1 = oi1;
                } else {
                    v2 = fmaxf(v2, ov1);
                }
            }
            if (lm == 0) {
                const int rloc = wn + rt * 16 + q * 4 + r;
                rv1[rloc][w & 1] = v1;
                ri1[rloc][w & 1] = i1;
                rv2[rloc][w & 1] = v2;
            }
        }
    }
    __syncthreads();  // rnA + rv* visible

    // ---- col path: rows m (m-strip), candidates n (n-strip), scale rnorm[n]
    if (!diag) {
        float rnn[4][4];
#pragma unroll
        for (int rt = 0; rt < 4; ++rt)
#pragma unroll
            for (int r = 0; r < 4; ++r) rnn[rt][r] = rnA[wn + rt * 16 + q * 4 + r];
#pragma unroll
        for (int ct = 0; ct < 4; ++ct) {
            float v1 = -3.4e38f, v2 = -3.4e38f;
            int i1 = 0x7fffffff;
#pragma unroll
            for (int rt = 0; rt < 4; ++rt) {
#pragma unroll
                for (int r = 0; r < 4; ++r) {
                    const float v = acc[rt][ct][r] * rnn[rt][r];
                    const int nn = n0 + wn + rt * 16 + q * 4 + r;
                    if (v > v1) { v2 = v1; v1 = v; i1 = nn; }
                    else if (v > v2) v2 = v;
                }
            }
#pragma unroll
            for (int d = 16; d < 64; d <<= 1) {
                const float ov1 = __shfl_xor(v1, d, 64);
                const int oi1 = __shfl_xor(i1, d, 64);
                const float ov2 = __shfl_xor(v2, d, 64);
                if (ov1 > v1 || (ov1 == v1 && oi1 < i1)) {
                    v2 = fmaxf(v1, ov2); v1 = ov1; i1 = oi1;
                } else {
                    v2 = fmaxf(v2, ov1);
                }
            }
            if (q == 0) {
                const int mloc = wm + ct * 16 + lm;
                cv1[mloc][w >> 1] = v1;
                ci1[mloc][w >> 1] = i1;
                cv2[mloc][w >> 1] = v2;
            }
        }
    }
    __syncthreads();

    if (tid < 128) {
        // row result -> slot bm, rows n-strip
        {
            float v1 = rv1[tid][0]; int i1 = ri1[tid][0]; float v2 = rv2[tid][0];
            const float ov1 = rv1[tid][1]; const int oi1 = ri1[tid][1]; const float ov2 = rv2[tid][1];
            if (ov1 > v1 || (ov1 == v1 && oi1 < i1)) { v2 = fmaxf(v1, ov2); v1 = ov1; i1 = oi1; }
            else v2 = fmaxf(v2, ov1);
            const size_t gi = (size_t)(batch * NTILES + bm) * N_ + n0 + tid;
            pval[gi] = v1; pidx[gi] = i1; pval2[gi] = v2;
        }
        // col result -> slot bn, rows m-strip
        if (!diag) {
            float v1 = cv1[tid][0]; int i1 = ci1[tid][0]; float v2 = cv2[tid][0];
            const float ov1 = cv1[tid][1]; const int oi1 = ci1[tid][1]; const float ov2 = cv2[tid][1];
            if (ov1 > v1 || (ov1 == v1 && oi1 < i1)) { v2 = fmaxf(v1, ov2); v1 = ov1; i1 = oi1; }
            else v2 = fmaxf(v2, ov1);
            const size_t gi = (size_t)(batch * NTILES + bn) * N_ + m0 + tid;
            pval[gi] = v1; pidx[gi] = i1; pval2[gi] = v2;
        }
    }
}

// -------------------------------------------------------------- combine ----
__global__ void combine_kernel(const float* __restrict__ pval, const int* __restrict__ pidx,
                               const float* __restrict__ pval2, int* __restrict__ fidx,
                               int* __restrict__ rcnt, int* __restrict__ ridx) {
    const int t = blockIdx.x * 256 + threadIdx.x;  // 16384
    const int batch = t >> 11, n = t & 2047;
    float v1 = -3.4e38f, v2 = -3.4e38f;
    int i1 = 0x7fffffff;
    for (int s = 0; s < NTILES; ++s) {
        const size_t gi = (size_t)(batch * NTILES + s) * N_ + n;
        const float ov1 = pval[gi]; const int oi1 = pidx[gi]; const float ov2 = pval2[gi];
        if (ov1 > v1 || (ov1 == v1 && oi1 < i1)) { v2 = fmaxf(v1, ov2); v1 = ov1; i1 = oi1; }
        else v2 = fmaxf(v2, ov1);
    }
    fidx[t] = i1;
    if (v1 - v2 < 1e-4f) {
        const int slot = atomicAdd(rcnt, 1);
        ridx[slot] = t;
    }
}

// --------------------------------------------------------------- rescue ----
// Exact fp32 re-argmax for near-tie rows, reading original x (coalesced over m).
__global__ __launch_bounds__(256) void rescue_kernel(const float* __restrict__ x,
                                                     const float* __restrict__ rnorm,
                                                     const int* __restrict__ rcnt,
                                                     const int* __restrict__ ridx,
                                                     int* __restrict__ fidx) {
    const int cnt = *rcnt;
    const int tid = threadIdx.x;
    __shared__ float bv[256];
    __shared__ int bi[256];
    for (int rr = blockIdx.x; rr < cnt; rr += gridDim.x) {
        const int t = ridx[rr];
        const int batch = t >> 11, n = t & 2047;
        const float* xb = x + (size_t)batch * CN_;
        float s[8];
#pragma unroll
        for (int k = 0; k < 8; ++k) s[k] = 0.f;
        for (int c = 0; c < C_; ++c) {
            const float xc = xb[(size_t)c * N_ + n];
            const float* xr = xb + (size_t)c * N_;
#pragma unroll
            for (int k = 0; k < 8; ++k) s[k] += xc * xr[tid + (k << 8)];
        }
        float best = -3.4e38f;
        int besti = 0x7fffffff;
#pragma unroll
        for (int k = 0; k < 8; ++k) {
            const int m = tid + (k << 8);
            const float v = s[k] * rnorm[batch * N_ + m];
            if (m != n && v > best) { best = v; besti = m; }
        }
        bv[tid] = best; bi[tid] = besti;
        __syncthreads();
        for (int sft = 128; sft > 0; sft >>= 1) {
            if (tid < sft) {
                const float ov = bv[tid + sft]; const int oi = bi[tid + sft];
                if (ov > bv[tid] || (ov == bv[tid] && oi < bi[tid])) { bv[tid] = ov; bi[tid] = oi; }
            }
            __syncthreads();
        }
        if (tid == 0) fidx[t] = bi[0];
        __syncthreads();
    }
}

// ------------------------------- finish: gate softmax + gather + outputs ---
// grid = 1024 blocks (batch = blk&7, 128 ntiles of 16 n), 256 threads.
__global__ __launch_bounds__(256) void finish_kernel(const float* __restrict__ x,
                                                     const __hip_bfloat16* __restrict__ hiT,
                                                     const __hip_bfloat16* __restrict__ loT,
                                                     const float* __restrict__ W,
                                                     const int* __restrict__ fidx,
                                                     float* __restrict__ out) {
    const int batch = blockIdx.x & 7;
    const int nt = blockIdx.x >> 3;  // 0..127
    const int n0 = nt << 4;
    const int t = threadIdx.x;
    const int i = t & 15, cg = t >> 4;  // cg 0..15, 16 c each

    __shared__ float Wl[1024];
    __shared__ int il[16];
    __shared__ float l0r[16][17], l1r[16][17];
    __shared__ float w0s[16], w1s[16];

    for (int u = t; u < 1024; u += 256) Wl[u] = W[u];
    if (t < 16) il[t] = fidx[batch * N_ + n0 + t];
    __syncthreads();

    const float* xb = x + (size_t)batch * CN_ + n0 + i;
    const int myidx = il[i];
    const size_t row = ((size_t)batch * N_ + myidx) * C_ + cg * 16;

    float fvv[16];
    {
        const bf16x8* hp = (const bf16x8*)(hiT + row);
        const bf16x8* lp = (const bf16x8*)(loT + row);
#pragma unroll
        for (int v8 = 0; v8 < 2; ++v8) {
            const bf16x8 h = hp[v8];
            const bf16x8 g = lp[v8];
#pragma unroll
            for (int e = 0; e < 8; ++e) fvv[v8 * 8 + e] = b2f(h[e]) + b2f(g[e]);
        }
    }

    float l0 = 0.f, l1 = 0.f;
#pragma unroll
    for (int cc = 0; cc < 16; ++cc) {
        const int c = cg * 16 + cc;
        const float xv = xb[(size_t)c * N_];
        l0 += xv * Wl[c] + fvv[cc] * Wl[256 + c];
        l1 += xv * Wl[512 + c] + fvv[cc] * Wl[768 + c];
    }
    l0r[cg][i] = l0;
    l1r[cg][i] = l1;
    __syncthreads();
    if (t < 16) {
        float L0 = 0.f, L1 = 0.f;
#pragma unroll
        for (int g = 0; g < 16; ++g) { L0 += l0r[g][t]; L1 += l1r[g][t]; }
        const float mx = fmaxf(L0, L1);
        const float e0 = expf(L0 - mx);
        const float e1 = expf(L1 - mx);
        const float inv = 1.0f / (e0 + e1);
        w0s[t] = e0 * inv;
        w1s[t] = e1 * inv;
    }
    __syncthreads();
    const float w0 = w0s[i], w1 = w1s[i];

#pragma unroll
    for (int cc = 0; cc < 16; ++cc) {
        const int c = cg * 16 + cc;
        const size_t off = (size_t)batch * CN_ + (size_t)c * N_ + n0 + i;
        const float xv = xb[(size_t)c * N_];  // L1-hot re-read
        out[off] = xv * w0 + fvv[cc] * w1;
        out[TOT_ + off] = fvv[cc];
    }
}

// ---------------------------------------------------------------------------
extern "C" void kernel_launch(void* const* d_in, const int* in_sizes, int n_in,
                              void* d_out, int out_size, void* d_ws, size_t ws_size,
                              hipStream_t stream) {
    const float* x = (const float*)d_in[0];
    const float* W = (const float*)d_in[1];
    float* out = (float*)d_out;

    const size_t BF_BYTES = (size_t)TOT_ * 2;             // 8.39 MB each
    const size_t NORM_BYTES = (size_t)B_ * N_ * 4;        // 64 KB
    const size_t P_BYTES = (size_t)B_ * NTILES * N_ * 4;  // 1 MB each

    uint8_t* p = (uint8_t*)d_ws;
    __hip_bfloat16* hiT = (__hip_bfloat16*)p; p += BF_BYTES;
    __hip_bfloat16* loT = (__hip_bfloat16*)p; p += BF_BYTES;
    float* rnorm = (float*)p; p += NORM_BYTES;
    float* normacc = (float*)p; p += NORM_BYTES;
    float* pval = (float*)p; p += P_BYTES;
    int* pidx = (int*)p; p += P_BYTES;
    float* pval2 = (float*)p; p += P_BYTES;
    int* fidx = (int*)p; p += NORM_BYTES;
    int* rcnt = (int*)p; p += 256;
    int* ridx = (int*)p; p += NORM_BYTES;

    hipMemsetAsync(rcnt, 0, 4, stream);
    hipMemsetAsync(normacc, 0, NORM_BYTES, stream);
    convert_kernel<<<1024, 256, 0, stream>>>(x, hiT, loT, normacc);
    rnorm_fin_kernel<<<64, 256, 0, stream>>>(normacc, rnorm);
    gram_mfma_kernel<<<B_ * NPAIRS, 256, 0, stream>>>(hiT, loT, rnorm, pval, pidx, pval2);
    combine_kernel<<<64, 256, 0, stream>>>(pval, pidx, pval2, fidx, rcnt, ridx);
    rescue_kernel<<<64, 256, 0, stream>>>(x, rnorm, rcnt, ridx, fidx);
    finish_kernel<<<1024, 256, 0, stream>>>(x, hiT, loT, W, fidx, out);
}